// Round 4
// baseline (121.864 us; speedup 1.0000x reference)
//
#include <hip/hip_runtime.h>
#include <hip/hip_bf16.h>

// Batched matmul: [24,1024,64] fp32 x [24,64,1024] fp32 -> [24,1024,1024] fp32.
// R9: store-locality retile. R8 A/B proved nt-vs-cached stores are equivalent
// (121.7 vs 122.2us) -> write MODE innocent; the bmm store stream (~2.2TB/s
// effective vs 6.2TB/s proven by the harness fill at 9% occupancy) is limited
// by address locality: old tiling assembled each 4KB output row from 8 blocks
// on 8 different XCDs. New tiling:
//   - block = 32 rows x 1024 cols: ONE writer per output row, each block
//     writes a contiguous 128KB slab, row-major store order.
//   - 1-D grid 768, XCD-swizzled: XCD x handles bh in [3x,3x+3) -> contiguous
//     12.6MB output region per XCD; its 3 B-panels (384KB) stay hot in its L2.
//   - wave = 32x256: acc[8] (128 VGPR), A-frags loaded once, 32 MFMAs/wave.
// Fragment layout / f2bs / MFMA order byte-identical to verified R8 -> same
// absmax. Reformat kernel unchanged from R8.

#define NN 1024

typedef __attribute__((ext_vector_type(4))) float  float4v;
typedef __attribute__((ext_vector_type(8))) short  bf16x8;    // 8 bf16 = 16 B
typedef __attribute__((ext_vector_type(16))) float floatx16;  // 32x32 MFMA acc

// fp32 -> bf16 bits, round-to-nearest-even (inputs finite)
__device__ __forceinline__ short f2bs(float f) {
    union { float f; unsigned u; } in;
    in.f = f;
    unsigned u = in.u;
    return (short)((u + 0x7FFFu + ((u >> 16) & 1u)) >> 16);
}

// Fragment layout (32x32x16 bf16; verified end-to-end R1-R3):
//   element (idx, k): tile = idx>>5, ks = k>>4, q = (k>>3)&1, j = k&7
//   lane = (idx&31) + q*32, short addr = ((bh*32+tile)*4 + ks)*512 + lane*8 + j
// A indexed by m over [m][k] row-major; B indexed by n over [k][n].

// Reformat: blocks 0..767 handle A (one task/thread), 768..1535 handle B.
__global__ __launch_bounds__(256) void reformat_AB(const float* __restrict__ A,
                                                   const float* __restrict__ B,
                                                   short* __restrict__ Aw,
                                                   short* __restrict__ Bw) {
    const int bid = blockIdx.x;
    if (bid < 768) {
        int task = bid * 256 + threadIdx.x;      // 0..196607  [bh][m][kg]
        int bh   = task >> 13;
        int rem  = task & 8191;
        int m    = rem >> 3;
        int kg   = rem & 7;
        const float4v* p = (const float4v*)(A + (size_t)task * 8);
        float4v v0 = __builtin_nontemporal_load(p);
        float4v v1 = __builtin_nontemporal_load(p + 1);
        int ks = kg >> 1, q = kg & 1;
        int mt = m >> 5;
        int lane = (m & 31) + (q << 5);
        size_t dst = ((size_t)((bh * 32 + mt) * 4 + ks)) * 512 + (size_t)lane * 8;
        bf16x8 o;
        o[0] = f2bs(v0.x); o[1] = f2bs(v0.y); o[2] = f2bs(v0.z); o[3] = f2bs(v0.w);
        o[4] = f2bs(v1.x); o[5] = f2bs(v1.y); o[6] = f2bs(v1.z); o[7] = f2bs(v1.w);
        *(bf16x8*)(Aw + dst) = o;
    } else {
        int task = (bid - 768) * 256 + threadIdx.x;  // 0..196607  [kg][bh][n]
        int kg   = task / 24576;                 // 0..7
        int rem  = task - kg * 24576;
        int bh   = rem >> 10;
        int n    = rem & 1023;
        const float* p = B + (size_t)bh * 65536 + (size_t)kg * 8192 + n;
        float v0 = __builtin_nontemporal_load(p + 0 * 1024);
        float v1 = __builtin_nontemporal_load(p + 1 * 1024);
        float v2 = __builtin_nontemporal_load(p + 2 * 1024);
        float v3 = __builtin_nontemporal_load(p + 3 * 1024);
        float v4 = __builtin_nontemporal_load(p + 4 * 1024);
        float v5 = __builtin_nontemporal_load(p + 5 * 1024);
        float v6 = __builtin_nontemporal_load(p + 6 * 1024);
        float v7 = __builtin_nontemporal_load(p + 7 * 1024);
        int ks = kg >> 1, q = kg & 1;
        int nt = n >> 5;
        int lane = (n & 31) + (q << 5);
        size_t dst = ((size_t)((bh * 32 + nt) * 4 + ks)) * 512 + (size_t)lane * 8;
        bf16x8 o;
        o[0] = f2bs(v0); o[1] = f2bs(v1); o[2] = f2bs(v2); o[3] = f2bs(v3);
        o[4] = f2bs(v4); o[5] = f2bs(v5); o[6] = f2bs(v6); o[7] = f2bs(v7);
        *(bf16x8*)(Bw + dst) = o;
    }
}

// GEMM, row-slab tiling. Block: 32 m-rows x 1024 n-cols of one bh.
// Wave w covers cols [w*256, w*256+256) = n-tiles [8w, 8w+8).
// Non-swapped mfma(a,b,acc): col = lane&31 -> n (contiguous across lanes),
// row = (r&3)+8*(r>>2)+4*(lane>>5) -> m. Plain cached stores (R8-verified),
// row-outer / n-inner order -> in-block store stream is address-ascending.
__global__ __launch_bounds__(256, 2) void bmm_rows(const short* __restrict__ Aw,
                                                   const short* __restrict__ Bw,
                                                   float* __restrict__ C) {
    // XCD swizzle: hardware round-robins blockIdx across 8 XCDs; remap so
    // XCD x gets orig ids [96x, 96x+96) -> bh in [3x,3x+3), ms all.
    const int nid  = blockIdx.x;           // 0..767
    const int orig = (nid & 7) * 96 + (nid >> 3);
    const int bh   = orig >> 5;            // 0..23
    const int ms   = orig & 31;            // m-slab (32 rows), = global m-tile
    const int tid  = threadIdx.x;
    const int lane = tid & 63;
    const int w    = tid >> 6;             // wave 0..3

    const short* Ab = Aw + ((size_t)((bh * 32 + ms) * 4)) * 512 + (size_t)lane * 8;
    const short* Bb = Bw + ((size_t)((bh * 32 + w * 8) * 4)) * 512 + (size_t)lane * 8;
    // B: next n-tile +2048 shorts, next ks +512 shorts. A: next ks +512.

    floatx16 acc[8];
    #pragma unroll
    for (int ni = 0; ni < 8; ++ni)
        #pragma unroll
        for (int r = 0; r < 16; ++r)
            acc[ni][r] = 0.0f;

    // A fragments for this m-tile, loaded once, reused across all 8 n-tiles.
    bf16x8 a[4];
    #pragma unroll
    for (int ks = 0; ks < 4; ++ks)
        a[ks] = *(const bf16x8*)(Ab + ks * 512);

    #pragma unroll
    for (int ks = 0; ks < 4; ++ks) {
        #pragma unroll
        for (int ni = 0; ni < 8; ++ni) {
            bf16x8 b = *(const bf16x8*)(Bb + ni * 2048 + ks * 512);
            acc[ni] = __builtin_amdgcn_mfma_f32_32x32x16_bf16(a[ks], b, acc[ni], 0, 0, 0);
        }
    }

    // Epilogue: row-outer, n-inner. Each store instr: lanes 0-31 cover one
    // 128B line of (row), lanes 32-63 the same n-range of (row+4).
    const int nc    = lane & 31;
    const int rbase = (lane >> 5) * 4;
    float* Cb = C + ((size_t)bh << 20)
                  + (size_t)(ms * 32) * NN
                  + w * 256 + nc;

    #pragma unroll
    for (int rr = 0; rr < 16; ++rr) {
        int row = rbase + (rr & 3) + ((rr >> 2) * 8);
        float* Crow = Cb + (size_t)row * NN;
        #pragma unroll
        for (int ni = 0; ni < 8; ++ni) {
            Crow[ni * 32] = acc[ni][rr];
        }
    }
}

extern "C" void kernel_launch(void* const* d_in, const int* in_sizes, int n_in,
                              void* d_out, int out_size, void* d_ws, size_t ws_size,
                              hipStream_t stream) {
    const float* x1 = (const float*)d_in[0];   // [2,12,1024,64]
    const float* x2 = (const float*)d_in[1];   // [2,12,64,1024]
    float* out = (float*)d_out;                // [2,12,1024,1024] fp32

    short* Aw = (short*)d_ws;                  // 1,572,864 bf16 = 3.1 MB
    short* Bw = Aw + 1572864;                  // 3.1 MB

    hipLaunchKernelGGL(reformat_AB, dim3(1536), dim3(256), 0, stream, x1, x2, Aw, Bw);
    hipLaunchKernelGGL(bmm_rows, dim3(768), dim3(256), 0, stream, Aw, Bw, out);
}